// Round 13
// baseline (4239.182 us; speedup 1.0000x reference)
//
#include <hip/hip_runtime.h>
#include <hip/hip_bf16.h>

#define N_TOK 8192
#define HD    2048
#define NE    8
#define FF    1024

using f32x4  = __attribute__((ext_vector_type(4))) float;
using bf16x8 = __attribute__((ext_vector_type(8))) __bf16;

__device__ __forceinline__ unsigned short f2bf(float f) {
  unsigned u = __float_as_uint(f);
  u += 0x7FFFu + ((u >> 16) & 1u);   // RTNE (inputs are finite/normal)
  return (unsigned short)(u >> 16);
}

__device__ __forceinline__ void gl_lds16(const void* g, void* l) {
  __builtin_amdgcn_global_load_lds((__attribute__((address_space(1))) void*)g,
                                   (__attribute__((address_space(3))) void*)l,
                                   16, 0, 0);
}

// Stage a 256-row x 64-col bf16 tile (32KB): 4 calls/thread, pre-swizzled global src.
__device__ __forceinline__ void stage256(const unsigned short* g, size_t lda, int k0,
                                         char* slotbase, int wv, int sr8, int scol) {
  #pragma unroll
  for (int c = 0; c < 4; ++c) {
    const int grp = c * 8 + wv;
    gl_lds16(g + (size_t)(grp * 8 + sr8) * lda + k0 + scol, slotbase + grp * 1024);
  }
}
// indexed variant: per-thread row base pointers (compacted token gather)
__device__ __forceinline__ void stage256i(const unsigned short* const aP[4], int k0,
                                          char* slotbase, int wv) {
  #pragma unroll
  for (int c = 0; c < 4; ++c) {
    const int grp = c * 8 + wv;
    gl_lds16(aP[c] + k0, slotbase + grp * 1024);
  }
}
// 128-row tile (16KB): 2 calls/thread.
__device__ __forceinline__ void stage128(const unsigned short* g, size_t lda, int k0,
                                         char* slotbase, int wv, int sr8, int scol) {
  #pragma unroll
  for (int c = 0; c < 2; ++c) {
    const int grp = c * 8 + wv;
    gl_lds16(g + (size_t)(grp * 8 + sr8) * lda + k0 + scol, slotbase + grp * 1024);
  }
}

// ---- tiled transpose + convert: in[z][R][C] fp32 -> out[z*out_z + c*ostride + r] bf16 ----
__global__ void k_tconv(const float* __restrict__ in, unsigned short* __restrict__ out,
                        int R, int C, size_t in_z, size_t out_z, size_t ostride) {
  __shared__ float tile[32][33];
  const int z = blockIdx.z;
  const int c0 = blockIdx.x * 32, r0 = blockIdx.y * 32;
  const int tx = threadIdx.x, ty = threadIdx.y;
  const float* ip = in + (size_t)z * in_z;
  unsigned short* op = out + (size_t)z * out_z;
  #pragma unroll
  for (int i = ty; i < 32; i += 8)
    tile[i][tx] = ip[(size_t)(r0 + i) * C + (c0 + tx)];
  __syncthreads();
  #pragma unroll
  for (int i = ty; i < 32; i += 8)
    op[(size_t)(c0 + i) * ostride + (r0 + tx)] = f2bf(tile[tx][i]);
}

// ---- router: w = relu(x @ W_router), fp32 exact; also emits x in bf16. ----
__global__ void k_router(const float* __restrict__ x, const float* __restrict__ Wr,
                         float* __restrict__ w, float* __restrict__ rout,
                         unsigned short* __restrict__ xb) {
  const int lane = threadIdx.x & 63, wv = threadIdx.x >> 6;
  const int n = blockIdx.x * 4 + wv;
  const float* xr = x + (size_t)n * HD + lane * 32;
  unsigned short* xbr = xb + (size_t)n * HD + lane * 32;
  const float* wbase = Wr + (size_t)lane * 32 * NE;
  float acc[8];
  #pragma unroll
  for (int e = 0; e < 8; ++e) acc[e] = 0.f;
  #pragma unroll
  for (int kk = 0; kk < 32; kk += 4) {
    float4 xv = *reinterpret_cast<const float4*>(xr + kk);
    ushort4 o;
    o.x = f2bf(xv.x); o.y = f2bf(xv.y); o.z = f2bf(xv.z); o.w = f2bf(xv.w);
    *reinterpret_cast<ushort4*>(xbr + kk) = o;
    #pragma unroll
    for (int t = 0; t < 4; ++t) {
      const float* wrow = wbase + (kk + t) * 8;
      float4 w0 = *reinterpret_cast<const float4*>(wrow);
      float4 w1 = *reinterpret_cast<const float4*>(wrow + 4);
      float xs = (t == 0) ? xv.x : (t == 1) ? xv.y : (t == 2) ? xv.z : xv.w;
      acc[0] += xs * w0.x; acc[1] += xs * w0.y; acc[2] += xs * w0.z; acc[3] += xs * w0.w;
      acc[4] += xs * w1.x; acc[5] += xs * w1.y; acc[6] += xs * w1.z; acc[7] += xs * w1.w;
    }
  }
  #pragma unroll
  for (int off = 32; off; off >>= 1) {
    #pragma unroll
    for (int e = 0; e < 8; ++e) acc[e] += __shfl_down(acc[e], off);
  }
  if (lane == 0) {
    #pragma unroll
    for (int e = 0; e < 8; ++e) {
      float v = acc[e] > 0.f ? acc[e] : 0.f;
      w[n * 8 + e] = v;
      rout[n * 8 + e] = v;
    }
  }
}

// ---- per-expert stable compaction + inverse map rev[n][e]=cm or -1 ----
__global__ void k_compact(const float* __restrict__ w, int* __restrict__ idx,
                          int* __restrict__ rev, int* __restrict__ cnt) {
  const int e = blockIdx.x;
  __shared__ int base;
  __shared__ int scan[4];
  if (threadIdx.x == 0) base = 0;
  __syncthreads();
  const int lane = threadIdx.x & 63, wvi = threadIdx.x >> 6;
  for (int c0 = 0; c0 < N_TOK; c0 += 256) {
    const int n = c0 + threadIdx.x;
    const bool act = w[n * 8 + e] > 0.f;
    unsigned long long m = __ballot(act);
    const int pre  = __popcll(m & ((1ull << lane) - 1ull));
    if (lane == 0) scan[wvi] = __popcll(m);
    __syncthreads();
    int woff = 0;
    #pragma unroll
    for (int i = 0; i < 4; ++i) if (i < wvi) woff += scan[i];
    const int tot = scan[0] + scan[1] + scan[2] + scan[3];
    const int pos = base + woff + pre;
    if (act) idx[e * N_TOK + pos] = n;
    rev[n * NE + e] = act ? pos : -1;
    __syncthreads();
    if (threadIdx.x == 0) base += tot;
    __syncthreads();
  }
  const int M = base;
  if (threadIdx.x == 0) cnt[e] = M;
  const int Mpad = (M + 255) & ~255;
  for (int i = M + threadIdx.x; i < Mpad; i += 256) idx[e * N_TOK + i] = 0;
}

// ---- selective zero: A2[n][g*FF..] = 0 for inactive (n, e0+g) pairs ----
__global__ void k_zero(unsigned short* __restrict__ A2, const int* __restrict__ rev,
                       int e0, int G, int k2g) {
  const int n = blockIdx.x;
  const ushort4 z = {0, 0, 0, 0};
  for (int g = 0; g < G; ++g) {
    if (rev[n * NE + e0 + g] < 0) {
      ushort4* p = reinterpret_cast<ushort4*>(A2 + (size_t)n * k2g + g * FF);
      p[threadIdx.x] = z;
    }
  }
}

// =======================================================================
// GEMM1: fused gate+up on COMPACTED tokens, 256x128 tile, BK=64,
// SINGLE-buffered 64KB LDS -> 2 blocks/CU (cross-block latency hiding).
// T2 swizzle unchanged. Epilogue silu(g)*u*w scattered to A2 token rows.
// =======================================================================
#define G1_PHASE(cpK) do {                                                       \
    const char* Ab_ = As + (wr * 64) * 128 + rb;                                 \
    const char* Bg_ = Bgs + (wc * 64) * 128 + rb;                                \
    const char* Bu_ = Bus + (wc * 64) * 128 + rb;                                \
    bf16x8 av_[4], bg_[4], bu_[4];                                               \
    _Pragma("unroll")                                                            \
    for (int i = 0; i < 4; ++i) av_[i] = *(const bf16x8*)(Ab_ + i * 2048 + (cpK)); \
    _Pragma("unroll")                                                            \
    for (int j = 0; j < 4; ++j) {                                                \
      bg_[j] = *(const bf16x8*)(Bg_ + j * 2048 + (cpK));                         \
      bu_[j] = *(const bf16x8*)(Bu_ + j * 2048 + (cpK));                         \
    }                                                                            \
    __builtin_amdgcn_s_setprio(1);                                               \
    _Pragma("unroll")                                                            \
    for (int i = 0; i < 4; ++i) {                                                \
      _Pragma("unroll")                                                          \
      for (int j = 0; j < 4; ++j) {                                              \
        ag[i][j] = __builtin_amdgcn_mfma_f32_16x16x32_bf16(av_[i], bg_[j], ag[i][j], 0,0,0); \
        au[i][j] = __builtin_amdgcn_mfma_f32_16x16x32_bf16(av_[i], bu_[j], au[i][j], 0,0,0); \
      }                                                                          \
    }                                                                            \
    __builtin_amdgcn_s_setprio(0);                                               \
  } while (0)

__global__ void __launch_bounds__(512, 4) k_gemm1(
    const unsigned short* __restrict__ xb,
    const unsigned short* __restrict__ Wg,
    const unsigned short* __restrict__ Wu,
    const float* __restrict__ w,
    const int* __restrict__ idx,
    const int* __restrict__ cnt,
    unsigned short* __restrict__ A2,
    int e0, int k2g, int nwg) {
  extern __shared__ char lds[];
  char* As  = lds;                  // 32768 (single slot)
  char* Bgs = lds + 32768;          // 16384
  char* Bus = lds + 49152;          // 16384  (total 65536 -> 2 blocks/CU)
  const int tid = threadIdx.x;
  const int l = tid & 63, wv = tid >> 6;

  // XCD-chunk bijective swizzle; 256 blocks/expert = 8f x 32y, 2f x 8y sub-chunks
  const int h = blockIdx.x;
  const int chunk = nwg >> 3;
  const int L = (h & 7) * chunk + (h >> 3);
  const int eloc = L >> 8;                 // 256 blocks/expert
  const int e = e0 + eloc;
  const int idxq = L & 255;
  const int sub = idxq >> 5;
  const int f = ((sub & 1) << 2) | ((idxq >> 3) & 3);
  const int y = ((sub >> 1) << 3) | (idxq & 7);
  const int bm = y << 8;                   // 256-row tile (compacted space)
  const int bf = f << 7;                   // 128-col f tile
  const int wr = wv >> 1, wc = wv & 1;     // 4M x 2N waves

  const int Me = cnt[e];
  if (bm >= Me) return;
  const int* idxe = idx + e * N_TOK;

  const unsigned short* gBg = Wg + ((size_t)e * FF + bf) * HD;
  const unsigned short* gBu = Wu + ((size_t)e * FF + bf) * HD;

  // staging: pre-swizzled global source, linear LDS dest (rule #21)
  const int sr8  = l >> 3;
  const int scol = ((l & 7) ^ sr8) << 3;   // elements
  // frag reads: same involution on the read side
  const int fr  = l & 15;
  const int rb  = fr << 7;                 // row byte (128B rows)
  const int kc  = (l >> 4) << 4;
  const int swz = (l & 7) << 4;
  const int cp0 = kc ^ swz;
  const int cp1 = (64 + kc) ^ swz;

  // per-thread A row base pointers (gathered via compacted index; block-constant)
  const unsigned short* aP[4];
  #pragma unroll
  for (int c = 0; c < 4; ++c)
    aP[c] = xb + (size_t)idxe[bm + (c * 8 + wv) * 8 + sr8] * HD + scol;

  f32x4 ag[4][4], au[4][4];
  const f32x4 zero = {0.f, 0.f, 0.f, 0.f};
  #pragma unroll
  for (int i = 0; i < 4; ++i) {
    #pragma unroll
    for (int j = 0; j < 4; ++j) { ag[i][j] = zero; au[i][j] = zero; }
  }

  // prologue: tile 0
  stage256i(aP, 0, As, wv);
  stage128(gBg, HD, 0, Bgs, wv, sr8, scol);
  stage128(gBu, HD, 0, Bus, wv, sr8, scol);
  asm volatile("s_waitcnt vmcnt(0)" ::: "memory");
  __builtin_amdgcn_s_barrier();
  __builtin_amdgcn_sched_barrier(0);

  const int NT = HD / 64;   // 32
  for (int t = 0; t < NT; ++t) {
    G1_PHASE(cp0);
    G1_PHASE(cp1);
    __builtin_amdgcn_sched_barrier(0);
    __builtin_amdgcn_s_barrier();          // all waves done reading tile t
    __builtin_amdgcn_sched_barrier(0);
    if (t + 1 < NT) {
      stage256i(aP, (t + 1) * 64, As, wv);
      stage128(gBg, HD, (t + 1) * 64, Bgs, wv, sr8, scol);
      stage128(gBu, HD, (t + 1) * 64, Bus, wv, sr8, scol);
    }
    asm volatile("s_waitcnt vmcnt(0)" ::: "memory");
    __builtin_amdgcn_s_barrier();          // tile t+1 ready
    __builtin_amdgcn_sched_barrier(0);
  }

  // epilogue: silu(g)*u*w -> A2 (scattered to original token rows).
  // Padded rows (cm in [Me,Mpad)) rewrite token0's exact value -> benign dup.
  const int orow = (l >> 4) << 2;
  #pragma unroll
  for (int am = 0; am < 4; ++am) {
    #pragma unroll
    for (int rr = 0; rr < 4; ++rr) {
      const int cm = bm + wr * 64 + am * 16 + orow + rr;
      const int n = idxe[cm];
      const float wn = w[n * 8 + e];
      size_t obase = (size_t)n * k2g + (size_t)eloc * FF + bf + wc * 64 + fr;
      #pragma unroll
      for (int j = 0; j < 4; ++j) {
        const float g = ag[am][j][rr];
        const float u = au[am][j][rr];
        const float s = g / (1.f + __expf(-g));
        A2[obase + j * 16] = f2bf(s * u * wn);
      }
    }
  }
}

// =======================================================================
// GEMM2 (dense): out(+)= A2 @ Wd. 256x256 tile, BK=64, waves 2M x 4N
// (per-wave 128x64). 2-slot dbuf, vmcnt(0)+1 barrier. (r7 proven)
// =======================================================================
#define G2_PHASE(cpK) do {                                                       \
    const char* Ab_ = As + rs * 32768 + (wr * 128) * 128 + rb;                   \
    const char* Bb_ = Bs + rs * 32768 + (wc * 64) * 128 + rb;                    \
    bf16x8 av_[8], bv_[4];                                                       \
    _Pragma("unroll")                                                            \
    for (int i = 0; i < 8; ++i) av_[i] = *(const bf16x8*)(Ab_ + i * 2048 + (cpK)); \
    _Pragma("unroll")                                                            \
    for (int j = 0; j < 4; ++j) bv_[j] = *(const bf16x8*)(Bb_ + j * 2048 + (cpK)); \
    __builtin_amdgcn_s_setprio(1);                                               \
    _Pragma("unroll")                                                            \
    for (int i = 0; i < 8; ++i) {                                                \
      _Pragma("unroll")                                                          \
      for (int j = 0; j < 4; ++j)                                                \
        acc[i][j] = __builtin_amdgcn_mfma_f32_16x16x32_bf16(av_[i], bv_[j], acc[i][j], 0,0,0); \
    }                                                                            \
    __builtin_amdgcn_s_setprio(0);                                               \
  } while (0)

__global__ void __launch_bounds__(512, 2) k_gemm2(
    const unsigned short* __restrict__ A2,
    const unsigned short* __restrict__ Wd,
    float* __restrict__ out,
    int k2g, int accum) {
  extern __shared__ char lds[];
  char* As = lds;                   // 2 x 32768
  char* Bs = lds + 65536;           // 2 x 32768 (total 131072)
  const int tid = threadIdx.x;
  const int l = tid & 63, wv = tid >> 6;

  const int h = blockIdx.x;
  const int L = (h & 7) * 32 + (h >> 3);
  const int y = L >> 3;                    // 32 m-blocks
  const int x = L & 7;                     // 8 n-blocks
  const int bm = y << 8;
  const int bn = x << 8;
  const int wr = wv >> 2, wc = wv & 3;     // 2M x 4N

  const unsigned short* gA = A2 + (size_t)bm * k2g;
  const unsigned short* gB = Wd + (size_t)bn * (NE * FF);

  const int sr8  = l >> 3;
  const int scol = ((l & 7) ^ sr8) << 3;
  const int fr  = l & 15;
  const int rb  = fr << 7;
  const int kc  = (l >> 4) << 4;
  const int swz = (l & 7) << 4;
  const int cp0 = kc ^ swz;
  const int cp1 = (64 + kc) ^ swz;

  f32x4 acc[8][4];
  const f32x4 zero = {0.f, 0.f, 0.f, 0.f};
  #pragma unroll
  for (int i = 0; i < 8; ++i) {
    #pragma unroll
    for (int j = 0; j < 4; ++j) acc[i][j] = zero;
  }

  stage256(gA, k2g, 0, As, wv, sr8, scol);
  stage256(gB, NE * FF, 0, Bs, wv, sr8, scol);
  asm volatile("s_waitcnt vmcnt(0)" ::: "memory");
  __builtin_amdgcn_s_barrier();
  __builtin_amdgcn_sched_barrier(0);

  const int NT = k2g / 64;
  for (int t = 0; t < NT; ++t) {
    const int tn = (t + 1 < NT) ? t + 1 : NT - 1;
    const int sw = (t + 1) & 1;
    const int rs = t & 1;
    stage256(gB, NE * FF, tn * 64, Bs + sw * 32768, wv, sr8, scol);
    G2_PHASE(cp0);
    stage256(gA, k2g, tn * 64, As + sw * 32768, wv, sr8, scol);
    G2_PHASE(cp1);
    asm volatile("s_waitcnt vmcnt(0)" ::: "memory");
    __builtin_amdgcn_s_barrier();
    __builtin_amdgcn_sched_barrier(0);
  }

  const int orow = (l >> 4) << 2;
  #pragma unroll
  for (int am = 0; am < 8; ++am) {
    #pragma unroll
    for (int rr = 0; rr < 4; ++rr) {
      const int n = bm + wr * 128 + am * 16 + orow + rr;
      float* op = out + (size_t)n * HD + bn + wc * 64 + fr;
      #pragma unroll
      for (int j = 0; j < 4; ++j) {
        const float v = acc[am][j][rr];
        op[j * 16] = accum ? (op[j * 16] + v) : v;
      }
    }
  }
}

extern "C" void kernel_launch(void* const* d_in, const int* in_sizes, int n_in,
                              void* d_out, int out_size, void* d_ws, size_t ws_size,
                              hipStream_t stream) {
  (void)in_sizes; (void)out_size;
  if (n_in < 5) return;
  const float* x  = (const float*)d_in[0];
  const float* Wr = (const float*)d_in[1];
  const float* Wg = (const float*)d_in[2];
  const float* Wu = (const float*)d_in[3];
  const float* Wd = (const float*)d_in[4];
  float* out  = (float*)d_out;
  float* rout = out + (size_t)N_TOK * HD;

  hipFuncSetAttribute((const void*)k_gemm1, hipFuncAttributeMaxDynamicSharedMemorySize, 65536);
  hipFuncSetAttribute((const void*)k_gemm2, hipFuncAttributeMaxDynamicSharedMemorySize, 131072);

  char* ws = (char*)d_ws;
  const size_t SZ_XB = (size_t)N_TOK * HD * 2;
  const size_t SZ_W  = (size_t)NE * HD * FF * 2;
  unsigned short* xb    = (unsigned short*)(ws);
  unsigned short* Wg_bt = (unsigned short*)(ws + SZ_XB);
  unsigned short* Wu_bt = (unsigned short*)(ws + SZ_XB + SZ_W);
  unsigned short* Wd_bt = (unsigned short*)(ws + SZ_XB + 2 * SZ_W);
  float*          wbuf  = (float*)(ws + SZ_XB + 3 * SZ_W);
  size_t off = SZ_XB + 3 * SZ_W + (size_t)N_TOK * NE * 4;
  int* idxbuf = (int*)(ws + off);  off += (size_t)NE * N_TOK * 4;
  int* revbuf = (int*)(ws + off);  off += (size_t)NE * N_TOK * 4;
  int* cntbuf = (int*)(ws + off);  off += 256;
  const size_t fixed = off;
  unsigned short* A2 = (unsigned short*)(ws + fixed);

  const size_t perE = (size_t)N_TOK * FF * 2;   // 16.8 MB per expert slab
  int G = 8;
  while (G > 1 && fixed + (size_t)G * perE > ws_size) G >>= 1;

  // weight transposes (fp32 -> bf16 B^T layouts)
  dim3 tb(32, 8);
  k_tconv<<<dim3(FF / 32, HD / 32, NE), tb, 0, stream>>>(
      Wg, Wg_bt, HD, FF, (size_t)HD * FF, (size_t)FF * HD, (size_t)HD);
  k_tconv<<<dim3(FF / 32, HD / 32, NE), tb, 0, stream>>>(
      Wu, Wu_bt, HD, FF, (size_t)HD * FF, (size_t)FF * HD, (size_t)HD);
  k_tconv<<<dim3(HD / 32, FF / 32, NE), tb, 0, stream>>>(
      Wd, Wd_bt, FF, HD, (size_t)FF * HD, (size_t)FF, (size_t)(NE * FF));

  // router (fp32 exact) -> wbuf + d_out router section; also emits xb (bf16)
  k_router<<<N_TOK / 4, 256, 0, stream>>>(x, Wr, wbuf, rout, xb);

  // per-expert token compaction (+ inverse map)
  k_compact<<<NE, 256, 0, stream>>>(wbuf, idxbuf, revbuf, cntbuf);

  // expert GEMMs (G experts per pass; accumulate across passes)
  const int k2g = G * FF;
  for (int e0 = 0; e0 < NE; e0 += G) {
    k_zero<<<N_TOK, 256, 0, stream>>>(A2, revbuf, e0, G, k2g);   // zero inactive rows only
    const int nwg1 = 256 * G;   // per expert: 8 f-blocks x 32 y-blocks
    k_gemm1<<<nwg1, 512, 65536, stream>>>(xb, Wg_bt, Wu_bt, wbuf, idxbuf, cntbuf,
                                          A2, e0, k2g, nwg1);
    k_gemm2<<<(N_TOK / 256) * (HD / 256), 512, 131072, stream>>>(
        A2, Wd_bt + (size_t)e0 * FF, out, k2g, e0 != 0);
  }
}

// Round 14
// 678.373 us; speedup vs baseline: 6.2490x; 6.2490x over previous
//
#include <hip/hip_runtime.h>
#include <hip/hip_bf16.h>

#define N_TOK 8192
#define HD    2048
#define NE    8
#define FF    1024

using f32x4  = __attribute__((ext_vector_type(4))) float;
using bf16x8 = __attribute__((ext_vector_type(8))) __bf16;

__device__ __forceinline__ unsigned short f2bf(float f) {
  unsigned u = __float_as_uint(f);
  u += 0x7FFFu + ((u >> 16) & 1u);   // RTNE (inputs are finite/normal)
  return (unsigned short)(u >> 16);
}

__device__ __forceinline__ void gl_lds16(const void* g, void* l) {
  __builtin_amdgcn_global_load_lds((__attribute__((address_space(1))) void*)g,
                                   (__attribute__((address_space(3))) void*)l,
                                   16, 0, 0);
}

// Stage a 256-row x 64-col bf16 tile (32KB): 4 calls/thread, pre-swizzled global src.
__device__ __forceinline__ void stage256(const unsigned short* g, size_t lda, int k0,
                                         char* slotbase, int wv, int sr8, int scol) {
  #pragma unroll
  for (int c = 0; c < 4; ++c) {
    const int grp = c * 8 + wv;
    gl_lds16(g + (size_t)(grp * 8 + sr8) * lda + k0 + scol, slotbase + grp * 1024);
  }
}
// indexed variant: per-thread row base pointers (compacted token gather)
__device__ __forceinline__ void stage256i(const unsigned short* const aP[4], int k0,
                                          char* slotbase, int wv) {
  #pragma unroll
  for (int c = 0; c < 4; ++c) {
    const int grp = c * 8 + wv;
    gl_lds16(aP[c] + k0, slotbase + grp * 1024);
  }
}
// 128-row tile (16KB): 2 calls/thread.
__device__ __forceinline__ void stage128(const unsigned short* g, size_t lda, int k0,
                                         char* slotbase, int wv, int sr8, int scol) {
  #pragma unroll
  for (int c = 0; c < 2; ++c) {
    const int grp = c * 8 + wv;
    gl_lds16(g + (size_t)(grp * 8 + sr8) * lda + k0 + scol, slotbase + grp * 1024);
  }
}

// ---- tiled transpose + convert: in[z][R][C] fp32 -> out[z*out_z + c*ostride + r] bf16 ----
// zmod: if z >= zsplit, switch to (in2, out2) -- used to fuse Wg+Wu transposes.
__global__ void k_tconv(const float* __restrict__ in, unsigned short* __restrict__ out,
                        const float* __restrict__ in2, unsigned short* __restrict__ out2,
                        int zsplit, int C, size_t in_z, size_t out_z, size_t ostride) {
  __shared__ float tile[32][33];
  int z = blockIdx.z;
  const float* ip;
  unsigned short* op;
  if (z >= zsplit) {
    z -= zsplit;
    ip = in2 + (size_t)z * in_z;
    op = out2 + (size_t)z * out_z;
  } else {
    ip = in + (size_t)z * in_z;
    op = out + (size_t)z * out_z;
  }
  const int c0 = blockIdx.x * 32, r0 = blockIdx.y * 32;
  const int tx = threadIdx.x, ty = threadIdx.y;
  #pragma unroll
  for (int i = ty; i < 32; i += 8)
    tile[i][tx] = ip[(size_t)(r0 + i) * C + (c0 + tx)];
  __syncthreads();
  #pragma unroll
  for (int i = ty; i < 32; i += 8)
    op[(size_t)(c0 + i) * ostride + (r0 + tx)] = f2bf(tile[tx][i]);
}

// ---- router: w = relu(x @ W_router), fp32 exact; also emits x in bf16. ----
__global__ void k_router(const float* __restrict__ x, const float* __restrict__ Wr,
                         float* __restrict__ w, float* __restrict__ rout,
                         unsigned short* __restrict__ xb) {
  const int lane = threadIdx.x & 63, wv = threadIdx.x >> 6;
  const int n = blockIdx.x * 4 + wv;
  const float* xr = x + (size_t)n * HD + lane * 32;
  unsigned short* xbr = xb + (size_t)n * HD + lane * 32;
  const float* wbase = Wr + (size_t)lane * 32 * NE;
  float acc[8];
  #pragma unroll
  for (int e = 0; e < 8; ++e) acc[e] = 0.f;
  #pragma unroll
  for (int kk = 0; kk < 32; kk += 4) {
    float4 xv = *reinterpret_cast<const float4*>(xr + kk);
    ushort4 o;
    o.x = f2bf(xv.x); o.y = f2bf(xv.y); o.z = f2bf(xv.z); o.w = f2bf(xv.w);
    *reinterpret_cast<ushort4*>(xbr + kk) = o;
    #pragma unroll
    for (int t = 0; t < 4; ++t) {
      const float* wrow = wbase + (kk + t) * 8;
      float4 w0 = *reinterpret_cast<const float4*>(wrow);
      float4 w1 = *reinterpret_cast<const float4*>(wrow + 4);
      float xs = (t == 0) ? xv.x : (t == 1) ? xv.y : (t == 2) ? xv.z : xv.w;
      acc[0] += xs * w0.x; acc[1] += xs * w0.y; acc[2] += xs * w0.z; acc[3] += xs * w0.w;
      acc[4] += xs * w1.x; acc[5] += xs * w1.y; acc[6] += xs * w1.z; acc[7] += xs * w1.w;
    }
  }
  #pragma unroll
  for (int off = 32; off; off >>= 1) {
    #pragma unroll
    for (int e = 0; e < 8; ++e) acc[e] += __shfl_down(acc[e], off);
  }
  if (lane == 0) {
    #pragma unroll
    for (int e = 0; e < 8; ++e) {
      float v = acc[e] > 0.f ? acc[e] : 0.f;
      w[n * 8 + e] = v;
      rout[n * 8 + e] = v;
    }
  }
}

// ---- per-expert stable compaction + inverse map rev[n][e]=cm or -1 ----
__global__ void k_compact(const float* __restrict__ w, int* __restrict__ idx,
                          int* __restrict__ rev, int* __restrict__ cnt) {
  const int e = blockIdx.x;
  __shared__ int base;
  __shared__ int scan[4];
  if (threadIdx.x == 0) base = 0;
  __syncthreads();
  const int lane = threadIdx.x & 63, wvi = threadIdx.x >> 6;
  for (int c0 = 0; c0 < N_TOK; c0 += 256) {
    const int n = c0 + threadIdx.x;
    const bool act = w[n * 8 + e] > 0.f;
    unsigned long long m = __ballot(act);
    const int pre  = __popcll(m & ((1ull << lane) - 1ull));
    if (lane == 0) scan[wvi] = __popcll(m);
    __syncthreads();
    int woff = 0;
    #pragma unroll
    for (int i = 0; i < 4; ++i) if (i < wvi) woff += scan[i];
    const int tot = scan[0] + scan[1] + scan[2] + scan[3];
    const int pos = base + woff + pre;
    if (act) idx[e * N_TOK + pos] = n;
    rev[n * NE + e] = act ? pos : -1;
    __syncthreads();
    if (threadIdx.x == 0) base += tot;
    __syncthreads();
  }
  const int M = base;
  if (threadIdx.x == 0) cnt[e] = M;
  const int Mpad = (M + 255) & ~255;
  for (int i = M + threadIdx.x; i < Mpad; i += 256) idx[e * N_TOK + i] = 0;
}

// ---- selective zero: A2[n][g*FF..] = 0 for inactive (n, e0+g) pairs ----
__global__ void k_zero(unsigned short* __restrict__ A2, const int* __restrict__ rev,
                       int e0, int G, int k2g) {
  const int n = blockIdx.x;
  const ushort4 z = {0, 0, 0, 0};
  for (int g = 0; g < G; ++g) {
    if (rev[n * NE + e0 + g] < 0) {
      ushort4* p = reinterpret_cast<ushort4*>(A2 + (size_t)n * k2g + g * FF);
      p[threadIdx.x] = z;
    }
  }
}

// =======================================================================
// GEMM1: fused gate+up on COMPACTED tokens, 256x128 tile, BK=64,
// 2-slot double-buffer, T2 swizzle, vmcnt(0)+1-barrier per iter (r7
// proven). Epilogue silu(g)*u*w scattered to original A2 token rows.
// NOTE: dual acc (ag+au = 128 VGPR) forces 1 block/CU -- do not cap
// VGPRs below ~160 (r13 lesson: launch_bounds(...,4) spilled acc, 6x).
// =======================================================================
#define G1_PHASE(cpK) do {                                                       \
    const char* Ab_ = As + rs * 32768 + (wr * 64) * 128 + rb;                    \
    const char* Bg_ = Bgs + rs * 16384 + (wc * 64) * 128 + rb;                   \
    const char* Bu_ = Bus + rs * 16384 + (wc * 64) * 128 + rb;                   \
    bf16x8 av_[4], bg_[4], bu_[4];                                               \
    _Pragma("unroll")                                                            \
    for (int i = 0; i < 4; ++i) av_[i] = *(const bf16x8*)(Ab_ + i * 2048 + (cpK)); \
    _Pragma("unroll")                                                            \
    for (int j = 0; j < 4; ++j) {                                                \
      bg_[j] = *(const bf16x8*)(Bg_ + j * 2048 + (cpK));                         \
      bu_[j] = *(const bf16x8*)(Bu_ + j * 2048 + (cpK));                         \
    }                                                                            \
    __builtin_amdgcn_s_setprio(1);                                               \
    _Pragma("unroll")                                                            \
    for (int i = 0; i < 4; ++i) {                                                \
      _Pragma("unroll")                                                          \
      for (int j = 0; j < 4; ++j) {                                              \
        ag[i][j] = __builtin_amdgcn_mfma_f32_16x16x32_bf16(av_[i], bg_[j], ag[i][j], 0,0,0); \
        au[i][j] = __builtin_amdgcn_mfma_f32_16x16x32_bf16(av_[i], bu_[j], au[i][j], 0,0,0); \
      }                                                                          \
    }                                                                            \
    __builtin_amdgcn_s_setprio(0);                                               \
  } while (0)

__global__ void __launch_bounds__(512, 2) k_gemm1(
    const unsigned short* __restrict__ xb,
    const unsigned short* __restrict__ Wg,
    const unsigned short* __restrict__ Wu,
    const float* __restrict__ w,
    const int* __restrict__ idx,
    const int* __restrict__ cnt,
    unsigned short* __restrict__ A2,
    int e0, int k2g, int nwg) {
  extern __shared__ char lds[];
  char* As  = lds;                  // 2 x 32768 = 65536
  char* Bgs = lds + 65536;          // 2 x 16384
  char* Bus = lds + 98304;          // 2 x 16384  (total 131072)
  const int tid = threadIdx.x;
  const int l = tid & 63, wv = tid >> 6;

  // XCD-chunk bijective swizzle; 256 blocks/expert = 8f x 32y, 2f x 8y sub-chunks
  const int h = blockIdx.x;
  const int chunk = nwg >> 3;
  const int L = (h & 7) * chunk + (h >> 3);
  const int eloc = L >> 8;                 // 256 blocks/expert
  const int e = e0 + eloc;
  const int idxq = L & 255;
  const int sub = idxq >> 5;
  const int f = ((sub & 1) << 2) | ((idxq >> 3) & 3);
  const int y = ((sub >> 1) << 3) | (idxq & 7);
  const int bm = y << 8;                   // 256-row tile (compacted space)
  const int bf = f << 7;                   // 128-col f tile
  const int wr = wv >> 1, wc = wv & 1;     // 4M x 2N waves

  const int Me = cnt[e];
  if (bm >= Me) return;
  const int* idxe = idx + e * N_TOK;

  const unsigned short* gBg = Wg + ((size_t)e * FF + bf) * HD;
  const unsigned short* gBu = Wu + ((size_t)e * FF + bf) * HD;

  // staging: pre-swizzled global source, linear LDS dest (rule #21)
  const int sr8  = l >> 3;
  const int scol = ((l & 7) ^ sr8) << 3;   // elements
  // frag reads: same involution on the read side
  const int fr  = l & 15;
  const int rb  = fr << 7;                 // row byte (128B rows)
  const int kc  = (l >> 4) << 4;
  const int swz = (l & 7) << 4;
  const int cp0 = kc ^ swz;
  const int cp1 = (64 + kc) ^ swz;

  // per-thread A row base pointers (gathered via compacted index; block-constant)
  const unsigned short* aP[4];
  #pragma unroll
  for (int c = 0; c < 4; ++c)
    aP[c] = xb + (size_t)idxe[bm + (c * 8 + wv) * 8 + sr8] * HD + scol;

  f32x4 ag[4][4], au[4][4];
  const f32x4 zero = {0.f, 0.f, 0.f, 0.f};
  #pragma unroll
  for (int i = 0; i < 4; ++i) {
    #pragma unroll
    for (int j = 0; j < 4; ++j) { ag[i][j] = zero; au[i][j] = zero; }
  }

  // prologue: tile 0 into slot 0
  stage256i(aP, 0, As, wv);
  stage128(gBg, HD, 0, Bgs, wv, sr8, scol);
  stage128(gBu, HD, 0, Bus, wv, sr8, scol);
  asm volatile("s_waitcnt vmcnt(0)" ::: "memory");
  __builtin_amdgcn_s_barrier();
  __builtin_amdgcn_sched_barrier(0);

  const int NT = HD / 64;   // 32
  for (int t = 0; t < NT; ++t) {
    const int tn = (t + 1 < NT) ? t + 1 : NT - 1;
    const int sw = (t + 1) & 1;
    const int rs = t & 1;
    stage128(gBg, HD, tn * 64, Bgs + sw * 16384, wv, sr8, scol);
    stage128(gBu, HD, tn * 64, Bus + sw * 16384, wv, sr8, scol);
    G1_PHASE(cp0);
    stage256i(aP, tn * 64, As + sw * 32768, wv);
    G1_PHASE(cp1);
    asm volatile("s_waitcnt vmcnt(0)" ::: "memory");
    __builtin_amdgcn_s_barrier();
    __builtin_amdgcn_sched_barrier(0);
  }

  // epilogue: silu(g)*u*w -> A2 (scattered to original token rows).
  // Padded rows (cm in [Me,Mpad)) rewrite token0's exact value -> benign dup.
  const int orow = (l >> 4) << 2;
  #pragma unroll
  for (int am = 0; am < 4; ++am) {
    #pragma unroll
    for (int rr = 0; rr < 4; ++rr) {
      const int cm = bm + wr * 64 + am * 16 + orow + rr;
      const int n = idxe[cm];
      const float wn = w[n * 8 + e];
      size_t obase = (size_t)n * k2g + (size_t)eloc * FF + bf + wc * 64 + fr;
      #pragma unroll
      for (int j = 0; j < 4; ++j) {
        const float g = ag[am][j][rr];
        const float u = au[am][j][rr];
        const float s = g / (1.f + __expf(-g));
        A2[obase + j * 16] = f2bf(s * u * wn);
      }
    }
  }
}

// =======================================================================
// GEMM2 (dense): out(+)= A2 @ Wd. 256x256 tile, BK=64, waves 2M x 4N
// (per-wave 128x64). 2-slot dbuf, vmcnt(0)+1 barrier. (r7 proven)
// =======================================================================
#define G2_PHASE(cpK) do {                                                       \
    const char* Ab_ = As + rs * 32768 + (wr * 128) * 128 + rb;                   \
    const char* Bb_ = Bs + rs * 32768 + (wc * 64) * 128 + rb;                    \
    bf16x8 av_[8], bv_[4];                                                       \
    _Pragma("unroll")                                                            \
    for (int i = 0; i < 8; ++i) av_[i] = *(const bf16x8*)(Ab_ + i * 2048 + (cpK)); \
    _Pragma("unroll")                                                            \
    for (int j = 0; j < 4; ++j) bv_[j] = *(const bf16x8*)(Bb_ + j * 2048 + (cpK)); \
    __builtin_amdgcn_s_setprio(1);                                               \
    _Pragma("unroll")                                                            \
    for (int i = 0; i < 8; ++i) {                                                \
      _Pragma("unroll")                                                          \
      for (int j = 0; j < 4; ++j)                                                \
        acc[i][j] = __builtin_amdgcn_mfma_f32_16x16x32_bf16(av_[i], bv_[j], acc[i][j], 0,0,0); \
    }                                                                            \
    __builtin_amdgcn_s_setprio(0);                                               \
  } while (0)

__global__ void __launch_bounds__(512, 2) k_gemm2(
    const unsigned short* __restrict__ A2,
    const unsigned short* __restrict__ Wd,
    float* __restrict__ out,
    int k2g, int accum) {
  extern __shared__ char lds[];
  char* As = lds;                   // 2 x 32768
  char* Bs = lds + 65536;           // 2 x 32768 (total 131072)
  const int tid = threadIdx.x;
  const int l = tid & 63, wv = tid >> 6;

  const int h = blockIdx.x;
  const int L = (h & 7) * 32 + (h >> 3);
  const int y = L >> 3;                    // 32 m-blocks
  const int x = L & 7;                     // 8 n-blocks
  const int bm = y << 8;
  const int bn = x << 8;
  const int wr = wv >> 2, wc = wv & 3;     // 2M x 4N

  const unsigned short* gA = A2 + (size_t)bm * k2g;
  const unsigned short* gB = Wd + (size_t)bn * (NE * FF);

  const int sr8  = l >> 3;
  const int scol = ((l & 7) ^ sr8) << 3;
  const int fr  = l & 15;
  const int rb  = fr << 7;
  const int kc  = (l >> 4) << 4;
  const int swz = (l & 7) << 4;
  const int cp0 = kc ^ swz;
  const int cp1 = (64 + kc) ^ swz;

  f32x4 acc[8][4];
  const f32x4 zero = {0.f, 0.f, 0.f, 0.f};
  #pragma unroll
  for (int i = 0; i < 8; ++i) {
    #pragma unroll
    for (int j = 0; j < 4; ++j) acc[i][j] = zero;
  }

  stage256(gA, k2g, 0, As, wv, sr8, scol);
  stage256(gB, NE * FF, 0, Bs, wv, sr8, scol);
  asm volatile("s_waitcnt vmcnt(0)" ::: "memory");
  __builtin_amdgcn_s_barrier();
  __builtin_amdgcn_sched_barrier(0);

  const int NT = k2g / 64;
  for (int t = 0; t < NT; ++t) {
    const int tn = (t + 1 < NT) ? t + 1 : NT - 1;
    const int sw = (t + 1) & 1;
    const int rs = t & 1;
    stage256(gB, NE * FF, tn * 64, Bs + sw * 32768, wv, sr8, scol);
    G2_PHASE(cp0);
    stage256(gA, k2g, tn * 64, As + sw * 32768, wv, sr8, scol);
    G2_PHASE(cp1);
    asm volatile("s_waitcnt vmcnt(0)" ::: "memory");
    __builtin_amdgcn_s_barrier();
    __builtin_amdgcn_sched_barrier(0);
  }

  const int orow = (l >> 4) << 2;
  #pragma unroll
  for (int am = 0; am < 8; ++am) {
    #pragma unroll
    for (int rr = 0; rr < 4; ++rr) {
      const int n = bm + wr * 128 + am * 16 + orow + rr;
      float* op = out + (size_t)n * HD + bn + wc * 64 + fr;
      #pragma unroll
      for (int j = 0; j < 4; ++j) {
        const float v = acc[am][j][rr];
        op[j * 16] = accum ? (op[j * 16] + v) : v;
      }
    }
  }
}

extern "C" void kernel_launch(void* const* d_in, const int* in_sizes, int n_in,
                              void* d_out, int out_size, void* d_ws, size_t ws_size,
                              hipStream_t stream) {
  (void)in_sizes; (void)out_size;
  if (n_in < 5) return;
  const float* x  = (const float*)d_in[0];
  const float* Wr = (const float*)d_in[1];
  const float* Wg = (const float*)d_in[2];
  const float* Wu = (const float*)d_in[3];
  const float* Wd = (const float*)d_in[4];
  float* out  = (float*)d_out;
  float* rout = out + (size_t)N_TOK * HD;

  hipFuncSetAttribute((const void*)k_gemm1, hipFuncAttributeMaxDynamicSharedMemorySize, 131072);
  hipFuncSetAttribute((const void*)k_gemm2, hipFuncAttributeMaxDynamicSharedMemorySize, 131072);

  char* ws = (char*)d_ws;
  const size_t SZ_XB = (size_t)N_TOK * HD * 2;
  const size_t SZ_W  = (size_t)NE * HD * FF * 2;
  unsigned short* xb    = (unsigned short*)(ws);
  unsigned short* Wg_bt = (unsigned short*)(ws + SZ_XB);
  unsigned short* Wu_bt = (unsigned short*)(ws + SZ_XB + SZ_W);
  unsigned short* Wd_bt = (unsigned short*)(ws + SZ_XB + 2 * SZ_W);
  float*          wbuf  = (float*)(ws + SZ_XB + 3 * SZ_W);
  size_t off = SZ_XB + 3 * SZ_W + (size_t)N_TOK * NE * 4;
  int* idxbuf = (int*)(ws + off);  off += (size_t)NE * N_TOK * 4;
  int* revbuf = (int*)(ws + off);  off += (size_t)NE * N_TOK * 4;
  int* cntbuf = (int*)(ws + off);  off += 256;
  const size_t fixed = off;
  unsigned short* A2 = (unsigned short*)(ws + fixed);

  const size_t perE = (size_t)N_TOK * FF * 2;   // 16.8 MB per expert slab
  int G = 8;
  while (G > 1 && fixed + (size_t)G * perE > ws_size) G >>= 1;

  // weight transposes (fp32 -> bf16 B^T layouts); Wg+Wu fused in one launch
  dim3 tb(32, 8);
  k_tconv<<<dim3(FF / 32, HD / 32, 2 * NE), tb, 0, stream>>>(
      Wg, Wg_bt, Wu, Wu_bt, NE, FF, (size_t)HD * FF, (size_t)FF * HD, (size_t)HD);
  k_tconv<<<dim3(HD / 32, FF / 32, NE), tb, 0, stream>>>(
      Wd, Wd_bt, Wd, Wd_bt, NE, HD, (size_t)FF * HD, (size_t)FF, (size_t)(NE * FF));

  // router (fp32 exact) -> wbuf + d_out router section; also emits xb (bf16)
  k_router<<<N_TOK / 4, 256, 0, stream>>>(x, Wr, wbuf, rout, xb);

  // per-expert token compaction (+ inverse map)
  k_compact<<<NE, 256, 0, stream>>>(wbuf, idxbuf, revbuf, cntbuf);

  // expert GEMMs (G experts per pass; accumulate across passes)
  const int k2g = G * FF;
  for (int e0 = 0; e0 < NE; e0 += G) {
    k_zero<<<N_TOK, 256, 0, stream>>>(A2, revbuf, e0, G, k2g);   // zero inactive rows only
    const int nwg1 = 256 * G;   // per expert: 8 f-blocks x 32 y-blocks
    k_gemm1<<<nwg1, 512, 131072, stream>>>(xb, Wg_bt, Wu_bt, wbuf, idxbuf, cntbuf,
                                           A2, e0, k2g, nwg1);
    k_gemm2<<<(N_TOK / 256) * (HD / 256), 512, 131072, stream>>>(
        A2, Wd_bt + (size_t)e0 * FF, out, k2g, e0 != 0);
  }
}